// Round 13
// baseline (470.851 us; speedup 1.0000x reference)
//
#include <hip/hip_runtime.h>

#define NN 100000
#define NE 1600000
#define HID 64
#define EPSV 1e-5f
#define NB_ATT 512
#define NGRP 12500               // NN/8 node-groups for slice gather

// bucketed CSR build
#define NBUK 391                 // ceil(100000/256), bucket = dst>>8
#define BCAP 4608                // slots per bucket (lambda~4092, +8 sigma)
#define BTILE 2048               // edges per bin tile
#define NTILES 782               // ceil(NE/BTILE)

// ---------- small scratch layout (float indices into ws) ----------
#define SM_SUMS(l)  ((l)*128)
#define SM_SUMSQ(l) ((l)*128 + 64)
#define SM_HS       512
#define SM_C        576
#define SM_HV       768          // 64 floats
#define SM_EOFF     832
#define SM_GCUR     1024         // 392 ints (zeroed by memset)
#define SM_ZEND     1424         // memset covers [0, SM_ZEND)
#define SM_GPART    1424         // 782*8 floats, all written before read (no zero needed)

// big buffers (float offsets)
#define NPAD        100352L
#define OFF_DINV    7684L
#define OFF_H       (OFF_DINV + NPAD)       // hb: PLANE-major bf16 [8][NN] uint4 (stage aliases)
#define OFF_Y32     (OFF_H + 6400000L)      // 3.2M uints (bf16x2), PLANE-major: 8 x NN x 16B
#define OFF_PART    (OFF_Y32 + 3200000L)    // NB_ATT*68
#define OFF_INT     (OFF_PART + 69632L)

static __device__ __forceinline__ unsigned bf16rne(float f) {
  unsigned u = __float_as_uint(f);
  return (u + 0x7fffu + ((u >> 16) & 1u)) >> 16;
}
static __device__ __forceinline__ unsigned packbf2(float lo, float hi) {
  return bf16rne(lo) | (bf16rne(hi) << 16);
}
static __device__ __forceinline__ float bflo(unsigned w) { return __uint_as_float(w << 16); }
static __device__ __forceinline__ float bfhi(unsigned w) { return __uint_as_float(w & 0xffff0000u); }

// GraphNorm affine from accumulated sums: gn(x) = sc*x + sh  (per feature j)
static __device__ __forceinline__ void gn_affine(int j, const float* w, const float* b,
                                                 const float* ms, const float* sums,
                                                 const float* sumsq, float& sc, float& sh) {
  const float invn = 1.0f / (float)NN;
  float mean = sums[j] * invn;
  float ex2  = sumsq[j] * invn;
  float m    = ms[j];
  float var  = ex2 - m * mean * mean * (2.0f - m);
  sc = w[j] * rsqrtf(var + EPSV);
  sh = b[j] - sc * m * mean;
}

// ---------------- pass 1: bin edges into per-bucket staging + gn0 block partials ----------------
__global__ __launch_bounds__(256) void k_bin(const int* __restrict__ src, const int* __restrict__ dst,
                                             const float* __restrict__ x,
                                             int* __restrict__ gcursor, unsigned* __restrict__ stage,
                                             float* __restrict__ gpart) {
  __shared__ int hist[NBUK], base[NBUK];
  __shared__ float gred[4][8];
  int t = threadIdx.x, lane = t & 63, w = t >> 6;
  long tile0 = (long)blockIdx.x * BTILE;
  for (int b = t; b < NBUK; b += 256) hist[b] = 0;
  __syncthreads();
  unsigned v[8]; int bk[8];
#pragma unroll
  for (int k = 0; k < 8; ++k) {
    long e = tile0 + k * 256 + t;
    if (e < NE) {
      int d = dst[e], s = src[e];
      bk[k] = d >> 8;
      v[k] = ((unsigned)(d & 255) << 24) | (unsigned)s;
      atomicAdd(&hist[bk[k]], 1);
    } else bk[k] = -1;
  }
  __syncthreads();
  for (int b = t; b < NBUK; b += 256) {
    int c = hist[b];
    base[b] = c ? atomicAdd(&gcursor[b], c) : 0;
    hist[b] = 0;
  }
  __syncthreads();
#pragma unroll
  for (int k = 0; k < 8; ++k) {
    if (bk[k] >= 0) {
      int bkk = bk[k];
      int off = atomicAdd(&hist[bkk], 1);
      stage[(long)bkk * BCAP + base[bkk] + off] = v[k];
    }
  }
  // gn0 stats over x -> per-block partial (no atomics)
  const float4* x4 = (const float4*)x;
  float4 s4 = make_float4(0.f, 0.f, 0.f, 0.f);
  float4 q4 = make_float4(0.f, 0.f, 0.f, 0.f);
  int stride = gridDim.x * 256;
  for (int i = blockIdx.x * 256 + t; i < NN; i += stride) {
    float4 xv = x4[i];
    s4.x += xv.x; s4.y += xv.y; s4.z += xv.z; s4.w += xv.w;
    q4.x += xv.x * xv.x; q4.y += xv.y * xv.y; q4.z += xv.z * xv.z; q4.w += xv.w * xv.w;
  }
#pragma unroll
  for (int off = 32; off; off >>= 1) {
    s4.x += __shfl_xor(s4.x, off, 64); s4.y += __shfl_xor(s4.y, off, 64);
    s4.z += __shfl_xor(s4.z, off, 64); s4.w += __shfl_xor(s4.w, off, 64);
    q4.x += __shfl_xor(q4.x, off, 64); q4.y += __shfl_xor(q4.y, off, 64);
    q4.z += __shfl_xor(q4.z, off, 64); q4.w += __shfl_xor(q4.w, off, 64);
  }
  if (lane == 0) {
    gred[w][0] = s4.x; gred[w][1] = s4.y; gred[w][2] = s4.z; gred[w][3] = s4.w;
    gred[w][4] = q4.x; gred[w][5] = q4.y; gred[w][6] = q4.z; gred[w][7] = q4.w;
  }
  __syncthreads();
  if (t < 8) gpart[blockIdx.x * 8 + t] = gred[0][t] + gred[1][t] + gred[2][t] + gred[3][t];
}

// ---------------- pass 1b: scan bucket counts -> boff; reduce gn0 partials ----------------
__global__ __launch_bounds__(512) void k_bscan(const int* __restrict__ gcursor,
                                               int* __restrict__ boff, int* __restrict__ rowptr,
                                               const float* __restrict__ gpart,
                                               float* __restrict__ sums0, float* __restrict__ sumsq0) {
  __shared__ int ws[8];
  __shared__ float gl[64][8];
  int t = threadIdx.x, lane = t & 63;
  int c = (t < NBUK) ? gcursor[t] : 0;
  int incl = c;
#pragma unroll
  for (int off = 1; off < 64; off <<= 1) {
    int u = __shfl_up(incl, off, 64);
    if (lane >= off) incl += u;
  }
  if (lane == 63) ws[t >> 6] = incl;
  __syncthreads();
  if (t == 0) {
    int s = 0;
#pragma unroll
    for (int w = 0; w < 8; ++w) { int tv = ws[w]; ws[w] = s; s += tv; }
  }
  __syncthreads();
  if (t < NBUK) boff[t] = incl - c + ws[t >> 6];
  if (t == 0) { boff[NBUK] = NE; rowptr[NN] = NE; }
  // gn0 partial reduce: 782 x 8 -> 8
  float acc = 0.f;
  int f = t & 7, r = t >> 3;            // 64 row-groups
  for (int i = r; i < NTILES; i += 64) acc += gpart[i * 8 + f];
  gl[r][f] = acc;
  __syncthreads();
  if (t < 8) {
    float s = 0.f;
#pragma unroll 16
    for (int rr = 0; rr < 64; ++rr) s += gl[rr][t];
    if (t < 4) sums0[t] = s;
    else sumsq0[t - 4] = s;
  }
}

// ---------------- pass 2: per-bucket counting sort -> col, rowptr, dinv ----------------
__global__ __launch_bounds__(256) void k_bsort(const unsigned* __restrict__ stage,
                                               const int* __restrict__ boff,
                                               int* __restrict__ col, int* __restrict__ rowptr,
                                               float* __restrict__ dinv) {
  __shared__ int hist[256], cur[256];
  __shared__ int ws[4];
  int b = blockIdx.x;
  int t = threadIdx.x, lane = t & 63;
  long sb = (long)b * BCAP;
  int b0 = boff[b], cb = boff[b + 1] - b0;
  hist[t] = 0;
  __syncthreads();
  for (int j = t; j < cb; j += 256)
    atomicAdd(&hist[stage[sb + j] >> 24], 1);
  __syncthreads();
  int c = hist[t];
  int incl = c;
#pragma unroll
  for (int off = 1; off < 64; off <<= 1) {
    int u = __shfl_up(incl, off, 64);
    if (lane >= off) incl += u;
  }
  if (lane == 63) ws[t >> 6] = incl;
  __syncthreads();
  int woff = 0;
  if (t >= 64) woff += ws[0];
  if (t >= 128) woff += ws[1];
  if (t >= 192) woff += ws[2];
  int gbase = b0 + (incl - c) + woff;
  int node = b * 256 + t;
  if (node < NN) {
    rowptr[node] = gbase;
    dinv[node] = rsqrtf((float)c + 1.0f);
  }
  cur[t] = gbase;
  __syncthreads();
  for (int j = t; j < cb; j += 256) {
    unsigned v = stage[sb + j];
    int pos = atomicAdd(&cur[v >> 24], 1);
    col[pos] = (int)(v & 0xffffffu);
  }
}

// ---------------- fused GraphNorm-apply + matmul + dinv prescale -> bf16 y (PLANE-major) ----------------
// h input (D==64) is PLANE-major bf16 [8][NN] uint4; x input (D==4) is node-major fp32.
template <int D>
__global__ __launch_bounds__(256) void k_mm(const float* __restrict__ hin, const float* __restrict__ W,
                                            const float* __restrict__ gw, const float* __restrict__ gb,
                                            const float* __restrict__ gms,
                                            const float* __restrict__ sums, const float* __restrict__ sumsq,
                                            const float* __restrict__ dinv,
                                            unsigned* __restrict__ y32) {
  __shared__ float4 Ws4[D][16];
  __shared__ float4 woff4[16];
  __shared__ float scale[D], shift[D];
  __shared__ float hl[16][68];      // stride 68: 16B-aligned rows, bank-shift 4
  int t = threadIdx.x;
  if (t < D) {
    float sc, sh;
    gn_affine(t, gw, gb, gms, sums, sumsq, sc, sh);
    scale[t] = sc; shift[t] = sh;
  }
  __syncthreads();
  for (int idx = t; idx < D * 64; idx += 256) {
    int k = idx >> 6;
    ((float*)Ws4)[idx] = scale[k] * W[idx];
  }
  __syncthreads();
  if (t < 64) {
    float o = 0.f;
#pragma unroll
    for (int k = 0; k < D; ++k) o += shift[k] * W[k * 64 + t];
    ((float*)woff4)[t] = o;
  }
  __syncthreads();

  int row = t >> 4, cg = t & 15;
  const int nG = NN / 16;  // 6250, exact
  for (int g = blockIdx.x; g < nG; g += gridDim.x) {
    int node = g * 16 + row;
    if (D == 64) {
      if (cg < 8) {   // plane cg, one uint4 = 8 bf16
        uint4 hw = ((const uint4*)hin)[(long)cg * NN + node];
        float* hd = &hl[row][cg * 8];
        hd[0] = bflo(hw.x); hd[1] = bfhi(hw.x); hd[2] = bflo(hw.y); hd[3] = bfhi(hw.y);
        hd[4] = bflo(hw.z); hd[5] = bfhi(hw.z); hd[6] = bflo(hw.w); hd[7] = bfhi(hw.w);
      }
    } else {
      if (t < 64) hl[t >> 2][t & 3] = hin[g * 64 + t];
    }
    __syncthreads();
    float4 acc = woff4[cg];
#pragma unroll
    for (int k = 0; k < D; ++k) {
      float hk = hl[row][k];
      float4 w4 = Ws4[k][cg];
      acc.x += hk * w4.x; acc.y += hk * w4.y;
      acc.z += hk * w4.z; acc.w += hk * w4.w;
    }
    float di = dinv[node];
    uint2 u;
    u.x = packbf2(di * acc.x, di * acc.y);
    u.y = packbf2(di * acc.z, di * acc.w);
    // y plane-major: plane = cg>>1, half = cg&1
    *(uint2*)(y32 + ((long)(cg >> 1) * NN + node) * 4 + (cg & 1) * 2) = u;
    __syncthreads();
  }
}

// ---------------- XCD-sliced CSR gather (plane-major y -> plane-major bf16 hb) ----------------
// 2-group interleave: each wave works on node-groups gA and gB=gA+gstride simultaneously,
// giving 2 independent col->y dependency chains (4 loads in flight per lane).
#define ACCF(F, WV) { F[0]+=bflo(WV.x); F[1]+=bfhi(WV.x); F[2]+=bflo(WV.y); F[3]+=bfhi(WV.y); \
                      F[4]+=bflo(WV.z); F[5]+=bfhi(WV.z); F[6]+=bflo(WV.w); F[7]+=bfhi(WV.w); }

template <bool PR>
__global__ __launch_bounds__(256) void k_gather_fin(const uint4* __restrict__ y4x,
                                                    const int* __restrict__ rowptr, const int* __restrict__ col,
                                                    const float* __restrict__ dinv,
                                                    const float* __restrict__ b, const float* __restrict__ a,
                                                    uint4* __restrict__ hb4p,
                                                    float* __restrict__ sums, float* __restrict__ sumsq) {
  __shared__ float ssum[8], ssq[8];
  __shared__ float bsh[8], ash[8];
  int t = threadIdx.x, lane = t & 63, w = t >> 6;
  int n = lane >> 3, j = lane & 7;
  int s = blockIdx.x & 7;
  const uint4* yp = y4x + (long)s * NN;   // this slice's plane
  if (t < 8) {
    ssum[t] = 0.f; ssq[t] = 0.f;
    bsh[t] = b[8 * s + t];
    ash[t] = PR ? a[8 * s + t] : 1.f;
  }
  __syncthreads();
  float sa[8] = {0,0,0,0,0,0,0,0}, qa[8] = {0,0,0,0,0,0,0,0};
  int gstride = (gridDim.x >> 3) * 4;
  for (int gA = (blockIdx.x >> 3) * 4 + w; gA < NGRP; gA += 2 * gstride) {
    int gB = gA + gstride;
    bool hasB = (gB < NGRP);
    int r = 0;
    if (lane < 9) r = rowptr[gA * 8 + lane];
    else if (lane >= 16 && lane < 25 && hasB) r = rowptr[gB * 8 + (lane - 16)];
    int p0A = __shfl(r, n, 64),      p1A = __shfl(r, n + 1, 64);
    int p0B = __shfl(r, 16 + n, 64), p1B = __shfl(r, 17 + n, 64);
    float fA[8] = {0,0,0,0,0,0,0,0}, fB[8] = {0,0,0,0,0,0,0,0};
    int pA = p0A + j, pB = p0B + j;
    while (pA < p1A && pB < p1B) {     // dual-chain main loop
      int cA = col[pA], cB = col[pB];
      uint4 wa = yp[cA];
      uint4 wb = yp[cB];
      ACCF(fA, wa); ACCF(fB, wb);
      pA += 8; pB += 8;
    }
    for (; pA + 8 < p1A; pA += 16) {   // A remainder, 2-deep
      int c0 = col[pA], c1 = col[pA + 8];
      uint4 wa = yp[c0]; uint4 wb = yp[c1];
      ACCF(fA, wa); ACCF(fA, wb);
    }
    if (pA < p1A) { uint4 wa = yp[col[pA]]; ACCF(fA, wa); }
    for (; pB + 8 < p1B; pB += 16) {   // B remainder, 2-deep
      int c0 = col[pB], c1 = col[pB + 8];
      uint4 wa = yp[c0]; uint4 wb = yp[c1];
      ACCF(fB, wa); ACCF(fB, wb);
    }
    if (pB < p1B) { uint4 wb = yp[col[pB]]; ACCF(fB, wb); }
    if (((p1A - p0A) & 7) == j) { uint4 wa = yp[gA * 8 + n]; ACCF(fA, wa); }     // self-loop A
    if (hasB && ((p1B - p0B) & 7) == j) { uint4 wb = yp[gB * 8 + n]; ACCF(fB, wb); } // self-loop B
#pragma unroll
    for (int k = 0; k < 8; ++k) {
      float vA = fA[k], vB = fB[k];
      vA += __shfl_xor(vA, 1, 64); vB += __shfl_xor(vB, 1, 64);
      vA += __shfl_xor(vA, 2, 64); vB += __shfl_xor(vB, 2, 64);
      vA += __shfl_xor(vA, 4, 64); vB += __shfl_xor(vB, 4, 64);
      fA[k] = vA; fB[k] = vB;
    }
    if (j == 0) {
      {
        int i = gA * 8 + n;
        float di = dinv[i];
        float vo[8];
#pragma unroll
        for (int k = 0; k < 8; ++k) {
          float v = di * fA[k] + bsh[k];
          if (PR && v < 0.f) v *= ash[k];
          vo[k] = v;
          sa[k] += v; qa[k] += v * v;
        }
        uint4 u;
        u.x = packbf2(vo[0], vo[1]); u.y = packbf2(vo[2], vo[3]);
        u.z = packbf2(vo[4], vo[5]); u.w = packbf2(vo[6], vo[7]);
        hb4p[(long)s * NN + i] = u;
      }
      if (hasB) {
        int i = gB * 8 + n;
        float di = dinv[i];
        float vo[8];
#pragma unroll
        for (int k = 0; k < 8; ++k) {
          float v = di * fB[k] + bsh[k];
          if (PR && v < 0.f) v *= ash[k];
          vo[k] = v;
          sa[k] += v; qa[k] += v * v;
        }
        uint4 u;
        u.x = packbf2(vo[0], vo[1]); u.y = packbf2(vo[2], vo[3]);
        u.z = packbf2(vo[4], vo[5]); u.w = packbf2(vo[6], vo[7]);
        hb4p[(long)s * NN + i] = u;
      }
    }
  }
  if (j == 0) {
#pragma unroll
    for (int k = 0; k < 8; ++k) { atomicAdd(&ssum[k], sa[k]); atomicAdd(&ssq[k], qa[k]); }
  }
  __syncthreads();
  if (t < 8) {
    atomicAdd(&sums[8 * s + t], ssum[t]);
    atomicAdd(&sumsq[8 * s + t], ssq[t]);
  }
}

// ---------------- Set2Set: fused attention pass (plane-major bf16 h) ----------------
// thread = (plane p = t>>5, node nn = t&31); chunk = 32 nodes; NN % 32 == 0.
__global__ __launch_bounds__(256) void k_att(const uint4* __restrict__ hb4p, const float* __restrict__ sm,
                                             float* __restrict__ part) {
  __shared__ float ldot[2][8][32];
  __shared__ float lr[8][32][8];
  __shared__ float lz[32];
  int t = threadIdx.x;
  int p = t >> 5, nn = t & 31;
  float hvr[8];
#pragma unroll
  for (int k = 0; k < 8; ++k) hvr[k] = sm[SM_HV + 8 * p + k];
  float eoff = sm[SM_EOFF];
  float m = -3.4e38f, z = 0.f;
  float r[8] = {0,0,0,0,0,0,0,0};
  int buf = 0;
  int stride = gridDim.x * 32;
  for (int i0 = blockIdx.x * 32; i0 < NN; i0 += stride) {
    int i = i0 + nn;
    uint4 hw = hb4p[(long)p * NN + i];
    float hx[8] = { bflo(hw.x), bfhi(hw.x), bflo(hw.y), bfhi(hw.y),
                    bflo(hw.z), bfhi(hw.z), bflo(hw.w), bfhi(hw.w) };
    float d = 0.f;
#pragma unroll
    for (int k = 0; k < 8; ++k) d += hx[k] * hvr[k];
    ldot[buf][p][nn] = d;
    __syncthreads();
    float e = eoff;
#pragma unroll
    for (int pp = 0; pp < 8; ++pp) e += ldot[buf][pp][nn];
    float mn = fmaxf(m, e);
    float sc = expf(m - mn);
    float pb = expf(e - mn);
    z = z * sc + pb;
#pragma unroll
    for (int k = 0; k < 8; ++k) r[k] = r[k] * sc + pb * hx[k];
    m = mn;
    buf ^= 1;
  }
  // block combine: m depends only on nn (identical across p and waves)
  float mb = m;
#pragma unroll
  for (int off = 16; off; off >>= 1) mb = fmaxf(mb, __shfl_xor(mb, off, 64));
  float scl = expf(m - mb);
#pragma unroll
  for (int k = 0; k < 8; ++k) lr[p][nn][k] = r[k] * scl;
  if (p == 0) lz[nn] = z * scl;
  __syncthreads();
  if (t < 64) {
    int pp = t >> 3, k = t & 7;
    float rb = 0.f;
#pragma unroll 8
    for (int n2 = 0; n2 < 32; ++n2) rb += lr[pp][n2][k];
    part[blockIdx.x * 68 + t] = rb;
  }
  if (t == 0) {
    float zb = 0.f;
#pragma unroll 8
    for (int n2 = 0; n2 < 32; ++n2) zb += lz[n2];
    part[blockIdx.x * 68 + 64] = mb;
    part[blockIdx.x * 68 + 65] = zb;
  }
}

// ---------------- Set2Set finish: reduce partials -> q_star -> LSTM(next) -> hv ----------------
// mode 0: boot (no reduce; LSTM from q*=0), 1: mid step, 2: final (write out, no LSTM)
__global__ __launch_bounds__(256) void k_attfin(const float* __restrict__ part,
                                                const float* __restrict__ gw, const float* __restrict__ gb,
                                                const float* __restrict__ gms,
                                                const float* __restrict__ sums, const float* __restrict__ sumsq,
                                                const float* __restrict__ Wih, const float* __restrict__ Whh,
                                                const float* __restrict__ bih, const float* __restrict__ bhh,
                                                float* __restrict__ sm, float* __restrict__ out, int mode) {
  __shared__ float hsL[64], cL[64], qsL[128], gL[256], red[256], sf[NB_ATT], rr4[4][64];
  int t = threadIdx.x, lane = t & 63, w = t >> 6;
  if (t < 64) { hsL[t] = sm[SM_HS + t]; cL[t] = sm[SM_C + t]; }
  __syncthreads();
  if (mode > 0) {
    float mv0 = part[t * 68 + 64];
    float mv1 = part[(t + 256) * 68 + 64];
    red[t] = fmaxf(mv0, mv1); __syncthreads();
    for (int s = 128; s; s >>= 1) { if (t < s) red[t] = fmaxf(red[t], red[t + s]); __syncthreads(); }
    float mg = red[0];
    __syncthreads();
    float sc0 = expf(mv0 - mg), sc1 = expf(mv1 - mg);
    sf[t] = sc0; sf[t + 256] = sc1;
    red[t] = part[t * 68 + 65] * sc0 + part[(t + 256) * 68 + 65] * sc1;
    __syncthreads();
    for (int s = 128; s; s >>= 1) { if (t < s) red[t] += red[t + s]; __syncthreads(); }
    float zg = red[0];
    __syncthreads();
    float racc = 0.f;
#pragma unroll 8
    for (int jx = 0; jx < 128; ++jx) {
      int bk = 4 * jx + w;
      racc += part[bk * 68 + lane] * sf[bk];
    }
    rr4[w][lane] = racc;
    __syncthreads();
    if (t < 64) {
      float rg = rr4[0][t] + rr4[1][t] + rr4[2][t] + rr4[3][t];
      float sc, sh;
      gn_affine(t, gw, gb, gms, sums, sumsq, sc, sh);
      float rr = sc * (rg / zg) + sh;
      qsL[t] = hsL[t]; qsL[64 + t] = rr;
      if (mode == 2) { out[t] = hsL[t]; out[64 + t] = rr; }
    }
  } else {
    if (t < 64) { qsL[t] = 0.f; qsL[64 + t] = 0.f; hsL[t] = 0.f; cL[t] = 0.f; }
  }
  __syncthreads();
  if (mode == 2) return;
  float g = bih[t] + bhh[t];
#pragma unroll 16
  for (int k = 0; k < 128; ++k) g += qsL[k] * Wih[t * 128 + k];
#pragma unroll 16
  for (int k = 0; k < 64; ++k) g += hsL[k] * Whh[t * 64 + k];
  gL[t] = g;
  __syncthreads();
  if (t < 64) {
    float ig = 1.f / (1.f + expf(-gL[t]));
    float fg = 1.f / (1.f + expf(-gL[64 + t]));
    float gg = tanhf(gL[128 + t]);
    float og = 1.f / (1.f + expf(-gL[192 + t]));
    float c = fg * cL[t] + ig * gg;
    float hsn = og * tanhf(c);
    sm[SM_C + t] = c;
    sm[SM_HS + t] = hsn;
    float sc, sh;
    gn_affine(t, gw, gb, gms, sums, sumsq, sc, sh);
    sm[SM_HV + t] = sc * hsn;
    red[t] = sh * hsn;
  }
  __syncthreads();
  if (t == 0) {
    float s = 0.f;
    for (int k = 0; k < 64; ++k) s += red[k];
    sm[SM_EOFF] = s;
  }
}

extern "C" void kernel_launch(void* const* d_in, const int* in_sizes, int n_in,
                              void* d_out, int out_size, void* d_ws, size_t ws_size,
                              hipStream_t stream) {
  const float* x     = (const float*)d_in[0];
  const float* gn0_w = (const float*)d_in[1];
  const float* gn0_b = (const float*)d_in[2];
  const float* gn0_ms= (const float*)d_in[3];
  const float* W1    = (const float*)d_in[4];
  const float* b1    = (const float*)d_in[5];
  const float* a1    = (const float*)d_in[6];
  const float* gn1_w = (const float*)d_in[7];
  const float* gn1_b = (const float*)d_in[8];
  const float* gn1_ms= (const float*)d_in[9];
  const float* W2    = (const float*)d_in[10];
  const float* b2    = (const float*)d_in[11];
  const float* a2    = (const float*)d_in[12];
  const float* gn2_w = (const float*)d_in[13];
  const float* gn2_b = (const float*)d_in[14];
  const float* gn2_ms= (const float*)d_in[15];
  const float* W3    = (const float*)d_in[16];
  const float* b3    = (const float*)d_in[17];
  const float* gn3_w = (const float*)d_in[18];
  const float* gn3_b = (const float*)d_in[19];
  const float* gn3_ms= (const float*)d_in[20];
  const float* Wih   = (const float*)d_in[21];
  const float* Whh   = (const float*)d_in[22];
  const float* bih   = (const float*)d_in[23];
  const float* bhh   = (const float*)d_in[24];
  const int*   eidx  = (const int*)d_in[25];
  const int* esrc = eidx;
  const int* edst = eidx + NE;

  float* sm   = (float*)d_ws;
  int* gcursor= (int*)(sm + SM_GCUR);          // 392 ints, zeroed by memset (counts)
  float* gpart= sm + SM_GPART;                 // 782*8, fully written each call
  float* dinv = sm + OFF_DINV;
  unsigned* stage = (unsigned*)(sm + OFF_H);   // aliases hb; dead before first gather
  uint4* hb4  = (uint4*)(sm + OFF_H);          // plane-major bf16 h [8][NN]
  unsigned* y32 = (unsigned*)(sm + OFF_Y32);
  const uint4* y4 = (const uint4*)y32;
  float* part = sm + OFF_PART;
  int* col    = (int*)(sm + OFF_INT);          // NE
  int* rowptr = col + NE;                      // NPAD (NN+1)
  int* boff   = rowptr + NPAD;                 // NBUK+1
  float* out  = (float*)d_out;

  hipMemsetAsync(sm, 0, SM_ZEND * sizeof(float), stream);

  // CSR build (gn0 stats via block partials, reduced in k_bscan)
  k_bin<<<NTILES, 256, 0, stream>>>(esrc, edst, x, gcursor, stage, gpart);
  k_bscan<<<1, 512, 0, stream>>>(gcursor, boff, rowptr, gpart,
                                 sm + SM_SUMS(0), sm + SM_SUMSQ(0));
  k_bsort<<<NBUK, 256, 0, stream>>>(stage, boff, col, rowptr, dinv);

  // layer 1
  k_mm<4><<<1024, 256, 0, stream>>>(x, W1, gn0_w, gn0_b, gn0_ms,
                                    sm + SM_SUMS(0), sm + SM_SUMSQ(0), dinv, y32);
  k_gather_fin<true><<<2048, 256, 0, stream>>>(y4, rowptr, col, dinv, b1, a1, hb4,
                                               sm + SM_SUMS(1), sm + SM_SUMSQ(1));
  // layer 2
  k_mm<64><<<1024, 256, 0, stream>>>((const float*)hb4, W2, gn1_w, gn1_b, gn1_ms,
                                     sm + SM_SUMS(1), sm + SM_SUMSQ(1), dinv, y32);
  k_gather_fin<true><<<2048, 256, 0, stream>>>(y4, rowptr, col, dinv, b2, a2, hb4,
                                               sm + SM_SUMS(2), sm + SM_SUMSQ(2));
  // layer 3 (no prelu)
  k_mm<64><<<1024, 256, 0, stream>>>((const float*)hb4, W3, gn2_w, gn2_b, gn2_ms,
                                     sm + SM_SUMS(2), sm + SM_SUMSQ(2), dinv, y32);
  k_gather_fin<false><<<2048, 256, 0, stream>>>(y4, rowptr, col, dinv, b3, nullptr, hb4,
                                                sm + SM_SUMS(3), sm + SM_SUMSQ(3));

  // Set2Set: boot LSTM (q*=0) + hv, then 3 steps
  k_attfin<<<1, 256, 0, stream>>>(part, gn3_w, gn3_b, gn3_ms,
                                  sm + SM_SUMS(3), sm + SM_SUMSQ(3),
                                  Wih, Whh, bih, bhh, sm, nullptr, 0);
  for (int s = 0; s < 3; ++s) {
    k_att<<<NB_ATT, 256, 0, stream>>>(hb4, sm, part);
    k_attfin<<<1, 256, 0, stream>>>(part, gn3_w, gn3_b, gn3_ms,
                                    sm + SM_SUMS(3), sm + SM_SUMSQ(3),
                                    Wih, Whh, bih, bhh, sm,
                                    (s == 2) ? out : nullptr, (s == 2) ? 2 : 1);
  }
}

// Round 14
// 418.931 us; speedup vs baseline: 1.1239x; 1.1239x over previous
//
#include <hip/hip_runtime.h>

#define NN 100000
#define NE 1600000
#define HID 64
#define EPSV 1e-5f
#define NB_ATT 512
#define NGRP 12500               // NN/8 node-groups for slice gather

// bucketed CSR build
#define NBUK 391                 // ceil(100000/256), bucket = dst>>8
#define BCAP 4608                // slots per bucket (lambda~4092, +8 sigma)
#define BTILE 2048               // edges per bin tile
#define NTILES 782               // ceil(NE/BTILE)

// ---------- small scratch layout (float indices into ws) ----------
#define SM_SUMS(l)  ((l)*128)
#define SM_SUMSQ(l) ((l)*128 + 64)
#define SM_HS       512
#define SM_C        576
#define SM_HV       768          // 64 floats
#define SM_EOFF     832
#define SM_GCUR     1024         // 392 ints (zeroed by memset)
#define SM_ZEND     1424         // memset covers [0, SM_ZEND)
#define SM_GPART    1424         // 782*8 floats, all written before read (no zero needed)

// big buffers (float offsets)
#define NPAD        100352L
#define OFF_DINV    7684L
#define OFF_H       (OFF_DINV + NPAD)       // hb: PLANE-major bf16 [8][NN] uint4 (stage aliases)
#define OFF_Y32     (OFF_H + 6400000L)      // 3.2M uints (bf16x2), PLANE-major: 8 x NN x 16B
#define OFF_PART    (OFF_Y32 + 3200000L)    // NB_ATT*68
#define OFF_INT     (OFF_PART + 69632L)

static __device__ __forceinline__ unsigned bf16rne(float f) {
  unsigned u = __float_as_uint(f);
  return (u + 0x7fffu + ((u >> 16) & 1u)) >> 16;
}
static __device__ __forceinline__ unsigned packbf2(float lo, float hi) {
  return bf16rne(lo) | (bf16rne(hi) << 16);
}
static __device__ __forceinline__ float bflo(unsigned w) { return __uint_as_float(w << 16); }
static __device__ __forceinline__ float bfhi(unsigned w) { return __uint_as_float(w & 0xffff0000u); }

// GraphNorm affine from accumulated sums: gn(x) = sc*x + sh  (per feature j)
static __device__ __forceinline__ void gn_affine(int j, const float* w, const float* b,
                                                 const float* ms, const float* sums,
                                                 const float* sumsq, float& sc, float& sh) {
  const float invn = 1.0f / (float)NN;
  float mean = sums[j] * invn;
  float ex2  = sumsq[j] * invn;
  float m    = ms[j];
  float var  = ex2 - m * mean * mean * (2.0f - m);
  sc = w[j] * rsqrtf(var + EPSV);
  sh = b[j] - sc * m * mean;
}

// ---------------- pass 1: bin edges into per-bucket staging + gn0 block partials ----------------
__global__ __launch_bounds__(256) void k_bin(const int* __restrict__ src, const int* __restrict__ dst,
                                             const float* __restrict__ x,
                                             int* __restrict__ gcursor, unsigned* __restrict__ stage,
                                             float* __restrict__ gpart) {
  __shared__ int hist[NBUK], base[NBUK];
  __shared__ float gred[4][8];
  int t = threadIdx.x, lane = t & 63, w = t >> 6;
  long tile0 = (long)blockIdx.x * BTILE;
  for (int b = t; b < NBUK; b += 256) hist[b] = 0;
  __syncthreads();
  unsigned v[8]; int bk[8];
#pragma unroll
  for (int k = 0; k < 8; ++k) {
    long e = tile0 + k * 256 + t;
    if (e < NE) {
      int d = dst[e], s = src[e];
      bk[k] = d >> 8;
      v[k] = ((unsigned)(d & 255) << 24) | (unsigned)s;
      atomicAdd(&hist[bk[k]], 1);
    } else bk[k] = -1;
  }
  __syncthreads();
  for (int b = t; b < NBUK; b += 256) {
    int c = hist[b];
    base[b] = c ? atomicAdd(&gcursor[b], c) : 0;
    hist[b] = 0;
  }
  __syncthreads();
#pragma unroll
  for (int k = 0; k < 8; ++k) {
    if (bk[k] >= 0) {
      int bkk = bk[k];
      int off = atomicAdd(&hist[bkk], 1);
      stage[(long)bkk * BCAP + base[bkk] + off] = v[k];
    }
  }
  // gn0 stats over x -> per-block partial (no atomics)
  const float4* x4 = (const float4*)x;
  float4 s4 = make_float4(0.f, 0.f, 0.f, 0.f);
  float4 q4 = make_float4(0.f, 0.f, 0.f, 0.f);
  int stride = gridDim.x * 256;
  for (int i = blockIdx.x * 256 + t; i < NN; i += stride) {
    float4 xv = x4[i];
    s4.x += xv.x; s4.y += xv.y; s4.z += xv.z; s4.w += xv.w;
    q4.x += xv.x * xv.x; q4.y += xv.y * xv.y; q4.z += xv.z * xv.z; q4.w += xv.w * xv.w;
  }
#pragma unroll
  for (int off = 32; off; off >>= 1) {
    s4.x += __shfl_xor(s4.x, off, 64); s4.y += __shfl_xor(s4.y, off, 64);
    s4.z += __shfl_xor(s4.z, off, 64); s4.w += __shfl_xor(s4.w, off, 64);
    q4.x += __shfl_xor(q4.x, off, 64); q4.y += __shfl_xor(q4.y, off, 64);
    q4.z += __shfl_xor(q4.z, off, 64); q4.w += __shfl_xor(q4.w, off, 64);
  }
  if (lane == 0) {
    gred[w][0] = s4.x; gred[w][1] = s4.y; gred[w][2] = s4.z; gred[w][3] = s4.w;
    gred[w][4] = q4.x; gred[w][5] = q4.y; gred[w][6] = q4.z; gred[w][7] = q4.w;
  }
  __syncthreads();
  if (t < 8) gpart[blockIdx.x * 8 + t] = gred[0][t] + gred[1][t] + gred[2][t] + gred[3][t];
}

// ---------------- pass 1b: scan bucket counts -> boff; reduce gn0 partials ----------------
__global__ __launch_bounds__(512) void k_bscan(const int* __restrict__ gcursor,
                                               int* __restrict__ boff, int* __restrict__ rowptr,
                                               const float* __restrict__ gpart,
                                               float* __restrict__ sums0, float* __restrict__ sumsq0) {
  __shared__ int ws[8];
  __shared__ float gl[64][8];
  int t = threadIdx.x, lane = t & 63;
  int c = (t < NBUK) ? gcursor[t] : 0;
  int incl = c;
#pragma unroll
  for (int off = 1; off < 64; off <<= 1) {
    int u = __shfl_up(incl, off, 64);
    if (lane >= off) incl += u;
  }
  if (lane == 63) ws[t >> 6] = incl;
  __syncthreads();
  if (t == 0) {
    int s = 0;
#pragma unroll
    for (int w = 0; w < 8; ++w) { int tv = ws[w]; ws[w] = s; s += tv; }
  }
  __syncthreads();
  if (t < NBUK) boff[t] = incl - c + ws[t >> 6];
  if (t == 0) { boff[NBUK] = NE; rowptr[NN] = NE; }
  // gn0 partial reduce: 782 x 8 -> 8
  float acc = 0.f;
  int f = t & 7, r = t >> 3;            // 64 row-groups
  for (int i = r; i < NTILES; i += 64) acc += gpart[i * 8 + f];
  gl[r][f] = acc;
  __syncthreads();
  if (t < 8) {
    float s = 0.f;
#pragma unroll 16
    for (int rr = 0; rr < 64; ++rr) s += gl[rr][t];
    if (t < 4) sums0[t] = s;
    else sumsq0[t - 4] = s;
  }
}

// ---------------- pass 2: per-bucket counting sort -> col, rowptr, dinv ----------------
__global__ __launch_bounds__(256) void k_bsort(const unsigned* __restrict__ stage,
                                               const int* __restrict__ boff,
                                               int* __restrict__ col, int* __restrict__ rowptr,
                                               float* __restrict__ dinv) {
  __shared__ int hist[256], cur[256];
  __shared__ int ws[4];
  int b = blockIdx.x;
  int t = threadIdx.x, lane = t & 63;
  long sb = (long)b * BCAP;
  int b0 = boff[b], cb = boff[b + 1] - b0;
  hist[t] = 0;
  __syncthreads();
  for (int j = t; j < cb; j += 256)
    atomicAdd(&hist[stage[sb + j] >> 24], 1);
  __syncthreads();
  int c = hist[t];
  int incl = c;
#pragma unroll
  for (int off = 1; off < 64; off <<= 1) {
    int u = __shfl_up(incl, off, 64);
    if (lane >= off) incl += u;
  }
  if (lane == 63) ws[t >> 6] = incl;
  __syncthreads();
  int woff = 0;
  if (t >= 64) woff += ws[0];
  if (t >= 128) woff += ws[1];
  if (t >= 192) woff += ws[2];
  int gbase = b0 + (incl - c) + woff;
  int node = b * 256 + t;
  if (node < NN) {
    rowptr[node] = gbase;
    dinv[node] = rsqrtf((float)c + 1.0f);
  }
  cur[t] = gbase;
  __syncthreads();
  for (int j = t; j < cb; j += 256) {
    unsigned v = stage[sb + j];
    int pos = atomicAdd(&cur[v >> 24], 1);
    col[pos] = (int)(v & 0xffffffu);
  }
}

// ---------------- fused GraphNorm-apply + matmul + dinv prescale -> bf16 y (PLANE-major) ----------------
// h input (D==64) is PLANE-major bf16 [8][NN] uint4; x input (D==4) is node-major fp32.
template <int D>
__global__ __launch_bounds__(256) void k_mm(const float* __restrict__ hin, const float* __restrict__ W,
                                            const float* __restrict__ gw, const float* __restrict__ gb,
                                            const float* __restrict__ gms,
                                            const float* __restrict__ sums, const float* __restrict__ sumsq,
                                            const float* __restrict__ dinv,
                                            unsigned* __restrict__ y32) {
  __shared__ float4 Ws4[D][16];
  __shared__ float4 woff4[16];
  __shared__ float scale[D], shift[D];
  __shared__ float hl[16][68];      // stride 68: 16B-aligned rows, bank-shift 4
  int t = threadIdx.x;
  if (t < D) {
    float sc, sh;
    gn_affine(t, gw, gb, gms, sums, sumsq, sc, sh);
    scale[t] = sc; shift[t] = sh;
  }
  __syncthreads();
  for (int idx = t; idx < D * 64; idx += 256) {
    int k = idx >> 6;
    ((float*)Ws4)[idx] = scale[k] * W[idx];
  }
  __syncthreads();
  if (t < 64) {
    float o = 0.f;
#pragma unroll
    for (int k = 0; k < D; ++k) o += shift[k] * W[k * 64 + t];
    ((float*)woff4)[t] = o;
  }
  __syncthreads();

  int row = t >> 4, cg = t & 15;
  const int nG = NN / 16;  // 6250, exact
  for (int g = blockIdx.x; g < nG; g += gridDim.x) {
    int node = g * 16 + row;
    if (D == 64) {
      if (cg < 8) {   // plane cg, one uint4 = 8 bf16
        uint4 hw = ((const uint4*)hin)[(long)cg * NN + node];
        float* hd = &hl[row][cg * 8];
        hd[0] = bflo(hw.x); hd[1] = bfhi(hw.x); hd[2] = bflo(hw.y); hd[3] = bfhi(hw.y);
        hd[4] = bflo(hw.z); hd[5] = bfhi(hw.z); hd[6] = bflo(hw.w); hd[7] = bfhi(hw.w);
      }
    } else {
      if (t < 64) hl[t >> 2][t & 3] = hin[g * 64 + t];
    }
    __syncthreads();
    float4 acc = woff4[cg];
#pragma unroll
    for (int k = 0; k < D; ++k) {
      float hk = hl[row][k];
      float4 w4 = Ws4[k][cg];
      acc.x += hk * w4.x; acc.y += hk * w4.y;
      acc.z += hk * w4.z; acc.w += hk * w4.w;
    }
    float di = dinv[node];
    uint2 u;
    u.x = packbf2(di * acc.x, di * acc.y);
    u.y = packbf2(di * acc.z, di * acc.w);
    // y plane-major: plane = cg>>1, half = cg&1
    *(uint2*)(y32 + ((long)(cg >> 1) * NN + node) * 4 + (cg & 1) * 2) = u;
    __syncthreads();
  }
}

// ---------------- XCD-sliced CSR gather (plane-major y -> plane-major bf16 hb) ----------------
// Round-12 structure (single chain, 2-edge unroll, next-group rowptr prefetch, regs-resident
// bias): VGPR~32 keeps 8 waves/SIMD — occupancy is the binding resource here (r13 lesson).
#define ACCW(WV) { f[0]+=bflo(WV.x); f[1]+=bfhi(WV.x); f[2]+=bflo(WV.y); f[3]+=bfhi(WV.y); \
                   f[4]+=bflo(WV.z); f[5]+=bfhi(WV.z); f[6]+=bflo(WV.w); f[7]+=bfhi(WV.w); }

template <bool PR>
__global__ __launch_bounds__(256) void k_gather_fin(const uint4* __restrict__ y4x,
                                                    const int* __restrict__ rowptr, const int* __restrict__ col,
                                                    const float* __restrict__ dinv,
                                                    const float* __restrict__ b, const float* __restrict__ a,
                                                    uint4* __restrict__ hb4p,
                                                    float* __restrict__ sums, float* __restrict__ sumsq) {
  __shared__ float ssum[8], ssq[8];
  int t = threadIdx.x, lane = t & 63, w = t >> 6;
  int n = lane >> 3, j = lane & 7;
  int s = blockIdx.x & 7;
  const uint4* yp = y4x + (long)s * NN;   // this slice's plane
  if (t < 8) { ssum[t] = 0.f; ssq[t] = 0.f; }
  __syncthreads();
  float bv[8], av[8];
#pragma unroll
  for (int k = 0; k < 8; ++k) {
    bv[k] = b[8 * s + k];
    av[k] = PR ? a[8 * s + k] : 1.f;
  }
  float sa[8] = {0,0,0,0,0,0,0,0}, qa[8] = {0,0,0,0,0,0,0,0};
  int gstride = (gridDim.x >> 3) * 4;
  int g = (blockIdx.x >> 3) * 4 + w;
  int rcur = 0;
  if (g < NGRP && lane < 9) rcur = rowptr[g * 8 + lane];
  while (g < NGRP) {
    int gn = g + gstride;
    int rn = 0;
    if (gn < NGRP && lane < 9) rn = rowptr[gn * 8 + lane];   // prefetch next group
    int i0 = g * 8;
    int p0 = __shfl(rcur, n, 64);
    int p1 = __shfl(rcur, n + 1, 64);
    float f[8] = {0,0,0,0,0,0,0,0};
    int p = p0 + j;
    // 2-edge unroll: 2 independent col loads -> 2 independent y loads in flight
    for (; p + 8 < p1; p += 16) {
      int c0 = col[p], c1 = col[p + 8];
      uint4 wa = yp[c0];
      uint4 wb = yp[c1];
      ACCW(wa); ACCW(wb);
    }
    if (p < p1) {
      uint4 wa = yp[col[p]];
      ACCW(wa);
    }
    if (((p1 - p0) & 7) == j) {           // self-loop: exactly one lane per node
      uint4 wa = yp[i0 + n];
      ACCW(wa);
    }
#pragma unroll
    for (int k = 0; k < 8; ++k) {
      float v = f[k];
      v += __shfl_xor(v, 1, 64);
      v += __shfl_xor(v, 2, 64);
      v += __shfl_xor(v, 4, 64);
      f[k] = v;
    }
    if (j == 0) {
      int i = i0 + n;
      float di = dinv[i];
      float vo[8];
#pragma unroll
      for (int k = 0; k < 8; ++k) {
        float v = di * f[k] + bv[k];
        if (PR && v < 0.f) v *= av[k];
        vo[k] = v;
        sa[k] += v; qa[k] += v * v;
      }
      uint4 u;
      u.x = packbf2(vo[0], vo[1]); u.y = packbf2(vo[2], vo[3]);
      u.z = packbf2(vo[4], vo[5]); u.w = packbf2(vo[6], vo[7]);
      hb4p[(long)s * NN + i] = u;                       // plane-major bf16
    }
    g = gn; rcur = rn;
  }
  if (j == 0) {
#pragma unroll
    for (int k = 0; k < 8; ++k) { atomicAdd(&ssum[k], sa[k]); atomicAdd(&ssq[k], qa[k]); }
  }
  __syncthreads();
  if (t < 8) {
    atomicAdd(&sums[8 * s + t], ssum[t]);
    atomicAdd(&sumsq[8 * s + t], ssq[t]);
  }
}

// ---------------- Set2Set: fused attention pass (plane-major bf16 h) ----------------
// thread = (plane p = t>>5, node nn = t&31); chunk = 32 nodes; NN % 32 == 0.
__global__ __launch_bounds__(256) void k_att(const uint4* __restrict__ hb4p, const float* __restrict__ sm,
                                             float* __restrict__ part) {
  __shared__ float ldot[2][8][32];
  __shared__ float lr[8][32][8];
  __shared__ float lz[32];
  int t = threadIdx.x;
  int p = t >> 5, nn = t & 31;
  float hvr[8];
#pragma unroll
  for (int k = 0; k < 8; ++k) hvr[k] = sm[SM_HV + 8 * p + k];
  float eoff = sm[SM_EOFF];
  float m = -3.4e38f, z = 0.f;
  float r[8] = {0,0,0,0,0,0,0,0};
  int buf = 0;
  int stride = gridDim.x * 32;
  for (int i0 = blockIdx.x * 32; i0 < NN; i0 += stride) {
    int i = i0 + nn;
    uint4 hw = hb4p[(long)p * NN + i];
    float hx[8] = { bflo(hw.x), bfhi(hw.x), bflo(hw.y), bfhi(hw.y),
                    bflo(hw.z), bfhi(hw.z), bflo(hw.w), bfhi(hw.w) };
    float d = 0.f;
#pragma unroll
    for (int k = 0; k < 8; ++k) d += hx[k] * hvr[k];
    ldot[buf][p][nn] = d;
    __syncthreads();
    float e = eoff;
#pragma unroll
    for (int pp = 0; pp < 8; ++pp) e += ldot[buf][pp][nn];
    float mn = fmaxf(m, e);
    float sc = expf(m - mn);
    float pb = expf(e - mn);
    z = z * sc + pb;
#pragma unroll
    for (int k = 0; k < 8; ++k) r[k] = r[k] * sc + pb * hx[k];
    m = mn;
    buf ^= 1;
  }
  // block combine: m depends only on nn (identical across p and waves)
  float mb = m;
#pragma unroll
  for (int off = 16; off; off >>= 1) mb = fmaxf(mb, __shfl_xor(mb, off, 64));
  float scl = expf(m - mb);
#pragma unroll
  for (int k = 0; k < 8; ++k) lr[p][nn][k] = r[k] * scl;
  if (p == 0) lz[nn] = z * scl;
  __syncthreads();
  if (t < 64) {
    int pp = t >> 3, k = t & 7;
    float rb = 0.f;
#pragma unroll 8
    for (int n2 = 0; n2 < 32; ++n2) rb += lr[pp][n2][k];
    part[blockIdx.x * 68 + t] = rb;
  }
  if (t == 0) {
    float zb = 0.f;
#pragma unroll 8
    for (int n2 = 0; n2 < 32; ++n2) zb += lz[n2];
    part[blockIdx.x * 68 + 64] = mb;
    part[blockIdx.x * 68 + 65] = zb;
  }
}

// ---------------- Set2Set finish: reduce partials -> q_star -> LSTM(next) -> hv ----------------
// mode 0: boot (no reduce; LSTM from q*=0), 1: mid step, 2: final (write out, no LSTM)
__global__ __launch_bounds__(256) void k_attfin(const float* __restrict__ part,
                                                const float* __restrict__ gw, const float* __restrict__ gb,
                                                const float* __restrict__ gms,
                                                const float* __restrict__ sums, const float* __restrict__ sumsq,
                                                const float* __restrict__ Wih, const float* __restrict__ Whh,
                                                const float* __restrict__ bih, const float* __restrict__ bhh,
                                                float* __restrict__ sm, float* __restrict__ out, int mode) {
  __shared__ float hsL[64], cL[64], qsL[128], gL[256], red[256], sf[NB_ATT], rr4[4][64];
  int t = threadIdx.x, lane = t & 63, w = t >> 6;
  if (t < 64) { hsL[t] = sm[SM_HS + t]; cL[t] = sm[SM_C + t]; }
  __syncthreads();
  if (mode > 0) {
    float mv0 = part[t * 68 + 64];
    float mv1 = part[(t + 256) * 68 + 64];
    red[t] = fmaxf(mv0, mv1); __syncthreads();
    for (int s = 128; s; s >>= 1) { if (t < s) red[t] = fmaxf(red[t], red[t + s]); __syncthreads(); }
    float mg = red[0];
    __syncthreads();
    float sc0 = expf(mv0 - mg), sc1 = expf(mv1 - mg);
    sf[t] = sc0; sf[t + 256] = sc1;
    red[t] = part[t * 68 + 65] * sc0 + part[(t + 256) * 68 + 65] * sc1;
    __syncthreads();
    for (int s = 128; s; s >>= 1) { if (t < s) red[t] += red[t + s]; __syncthreads(); }
    float zg = red[0];
    __syncthreads();
    float racc = 0.f;
#pragma unroll 8
    for (int jx = 0; jx < 128; ++jx) {
      int bk = 4 * jx + w;
      racc += part[bk * 68 + lane] * sf[bk];
    }
    rr4[w][lane] = racc;
    __syncthreads();
    if (t < 64) {
      float rg = rr4[0][t] + rr4[1][t] + rr4[2][t] + rr4[3][t];
      float sc, sh;
      gn_affine(t, gw, gb, gms, sums, sumsq, sc, sh);
      float rr = sc * (rg / zg) + sh;
      qsL[t] = hsL[t]; qsL[64 + t] = rr;
      if (mode == 2) { out[t] = hsL[t]; out[64 + t] = rr; }
    }
  } else {
    if (t < 64) { qsL[t] = 0.f; qsL[64 + t] = 0.f; hsL[t] = 0.f; cL[t] = 0.f; }
  }
  __syncthreads();
  if (mode == 2) return;
  float g = bih[t] + bhh[t];
#pragma unroll 16
  for (int k = 0; k < 128; ++k) g += qsL[k] * Wih[t * 128 + k];
#pragma unroll 16
  for (int k = 0; k < 64; ++k) g += hsL[k] * Whh[t * 64 + k];
  gL[t] = g;
  __syncthreads();
  if (t < 64) {
    float ig = 1.f / (1.f + expf(-gL[t]));
    float fg = 1.f / (1.f + expf(-gL[64 + t]));
    float gg = tanhf(gL[128 + t]);
    float og = 1.f / (1.f + expf(-gL[192 + t]));
    float c = fg * cL[t] + ig * gg;
    float hsn = og * tanhf(c);
    sm[SM_C + t] = c;
    sm[SM_HS + t] = hsn;
    float sc, sh;
    gn_affine(t, gw, gb, gms, sums, sumsq, sc, sh);
    sm[SM_HV + t] = sc * hsn;
    red[t] = sh * hsn;
  }
  __syncthreads();
  if (t == 0) {
    float s = 0.f;
    for (int k = 0; k < 64; ++k) s += red[k];
    sm[SM_EOFF] = s;
  }
}

extern "C" void kernel_launch(void* const* d_in, const int* in_sizes, int n_in,
                              void* d_out, int out_size, void* d_ws, size_t ws_size,
                              hipStream_t stream) {
  const float* x     = (const float*)d_in[0];
  const float* gn0_w = (const float*)d_in[1];
  const float* gn0_b = (const float*)d_in[2];
  const float* gn0_ms= (const float*)d_in[3];
  const float* W1    = (const float*)d_in[4];
  const float* b1    = (const float*)d_in[5];
  const float* a1    = (const float*)d_in[6];
  const float* gn1_w = (const float*)d_in[7];
  const float* gn1_b = (const float*)d_in[8];
  const float* gn1_ms= (const float*)d_in[9];
  const float* W2    = (const float*)d_in[10];
  const float* b2    = (const float*)d_in[11];
  const float* a2    = (const float*)d_in[12];
  const float* gn2_w = (const float*)d_in[13];
  const float* gn2_b = (const float*)d_in[14];
  const float* gn2_ms= (const float*)d_in[15];
  const float* W3    = (const float*)d_in[16];
  const float* b3    = (const float*)d_in[17];
  const float* gn3_w = (const float*)d_in[18];
  const float* gn3_b = (const float*)d_in[19];
  const float* gn3_ms= (const float*)d_in[20];
  const float* Wih   = (const float*)d_in[21];
  const float* Whh   = (const float*)d_in[22];
  const float* bih   = (const float*)d_in[23];
  const float* bhh   = (const float*)d_in[24];
  const int*   eidx  = (const int*)d_in[25];
  const int* esrc = eidx;
  const int* edst = eidx + NE;

  float* sm   = (float*)d_ws;
  int* gcursor= (int*)(sm + SM_GCUR);          // 392 ints, zeroed by memset (counts)
  float* gpart= sm + SM_GPART;                 // 782*8, fully written each call
  float* dinv = sm + OFF_DINV;
  unsigned* stage = (unsigned*)(sm + OFF_H);   // aliases hb; dead before first gather
  uint4* hb4  = (uint4*)(sm + OFF_H);          // plane-major bf16 h [8][NN]
  unsigned* y32 = (unsigned*)(sm + OFF_Y32);
  const uint4* y4 = (const uint4*)y32;
  float* part = sm + OFF_PART;
  int* col    = (int*)(sm + OFF_INT);          // NE
  int* rowptr = col + NE;                      // NPAD (NN+1)
  int* boff   = rowptr + NPAD;                 // NBUK+1
  float* out  = (float*)d_out;

  hipMemsetAsync(sm, 0, SM_ZEND * sizeof(float), stream);

  // CSR build (gn0 stats via block partials, reduced in k_bscan)
  k_bin<<<NTILES, 256, 0, stream>>>(esrc, edst, x, gcursor, stage, gpart);
  k_bscan<<<1, 512, 0, stream>>>(gcursor, boff, rowptr, gpart,
                                 sm + SM_SUMS(0), sm + SM_SUMSQ(0));
  k_bsort<<<NBUK, 256, 0, stream>>>(stage, boff, col, rowptr, dinv);

  // layer 1
  k_mm<4><<<1024, 256, 0, stream>>>(x, W1, gn0_w, gn0_b, gn0_ms,
                                    sm + SM_SUMS(0), sm + SM_SUMSQ(0), dinv, y32);
  k_gather_fin<true><<<2048, 256, 0, stream>>>(y4, rowptr, col, dinv, b1, a1, hb4,
                                               sm + SM_SUMS(1), sm + SM_SUMSQ(1));
  // layer 2
  k_mm<64><<<1024, 256, 0, stream>>>((const float*)hb4, W2, gn1_w, gn1_b, gn1_ms,
                                     sm + SM_SUMS(1), sm + SM_SUMSQ(1), dinv, y32);
  k_gather_fin<true><<<2048, 256, 0, stream>>>(y4, rowptr, col, dinv, b2, a2, hb4,
                                               sm + SM_SUMS(2), sm + SM_SUMSQ(2));
  // layer 3 (no prelu)
  k_mm<64><<<1024, 256, 0, stream>>>((const float*)hb4, W3, gn2_w, gn2_b, gn2_ms,
                                     sm + SM_SUMS(2), sm + SM_SUMSQ(2), dinv, y32);
  k_gather_fin<false><<<2048, 256, 0, stream>>>(y4, rowptr, col, dinv, b3, nullptr, hb4,
                                                sm + SM_SUMS(3), sm + SM_SUMSQ(3));

  // Set2Set: boot LSTM (q*=0) + hv, then 3 steps
  k_attfin<<<1, 256, 0, stream>>>(part, gn3_w, gn3_b, gn3_ms,
                                  sm + SM_SUMS(3), sm + SM_SUMSQ(3),
                                  Wih, Whh, bih, bhh, sm, nullptr, 0);
  for (int s = 0; s < 3; ++s) {
    k_att<<<NB_ATT, 256, 0, stream>>>(hb4, sm, part);
    k_attfin<<<1, 256, 0, stream>>>(part, gn3_w, gn3_b, gn3_ms,
                                    sm + SM_SUMS(3), sm + SM_SUMSQ(3),
                                    Wih, Whh, bih, bhh, sm,
                                    (s == 2) ? out : nullptr, (s == 2) ? 2 : 1);
  }
}